// Round 10
// baseline (128.378 us; speedup 1.0000x reference)
//
#include <hip/hip_runtime.h>

#define BB 256
#define TT 256
#define HH 64

typedef _Float16 half8 __attribute__((ext_vector_type(8)));
typedef _Float16 half4 __attribute__((ext_vector_type(4)));
typedef __fp16 fp16x2 __attribute__((ext_vector_type(2)));
typedef float floatx4 __attribute__((ext_vector_type(4)));

// ---------------------------------------------------------------------------
// prep: blocks 0..63   -> rpeh[i] = (f16) rpe[i]  (rows 0..255)
//       blocks 64..255 -> WT[(w*64+n)][k] = (f16) W_w[k][n]
// ---------------------------------------------------------------------------
__global__ __launch_bounds__(256) void prep(
    const float* __restrict__ rpe,
    const float* __restrict__ Wk, const float* __restrict__ Wq, const float* __restrict__ Wv,
    _Float16* __restrict__ rpeh, _Float16* __restrict__ WT)
{
    const int bid = blockIdx.x, tid = threadIdx.x;
    if (bid < 64) {
        const int i = bid * 256 + tid;
        rpeh[i] = (_Float16)rpe[i];
    } else {
        const int wsel = (bid - 64) >> 6;          // 0=k, 1=q, 2=v
        const int n    = (bid - 64) & 63;
        const float* W = wsel == 0 ? Wk : (wsel == 1 ? Wq : Wv);
        WT[(size_t)(wsel * 64 + n) * 256 + tid] = (_Float16)W[tid * HH + n];
    }
}

// per-tile pos-score slot pool: pair j = t>>1 shares width V_j
__device__ __forceinline__ int slot_width(int t) {
    const int j = t >> 1;
    return (j < 2) ? 72 : (32 * j + 40);
}
__device__ __forceinline__ int slot_off(int t) {      // halves, rel. to pool
    const int j = t >> 1;
    const int V = (j < 2) ? 72 : (32 * j + 40);
    const int S = (j == 0) ? 0 : (j == 1) ? 72 : (16 * j * j + 24 * j + 32);
    return 32 * S + (t & 1) * 16 * V;
}

// swapped content + in-reg exp: D[s][q] (col=q=l) -> exp -> f16 pack
__device__ __forceinline__ void score_exp(
    const _Float16* __restrict__ Klds, const _Float16* __restrict__ slot,
    int Vs, int st, int diagSt, int l, int quad,
    half8 qa, half8 qb, float& sum, unsigned& pk0, unsigned& pk1)
{
    const _Float16* kp = &Klds[(st * 16 + l) * 76 + quad * 8];
    const half8 kf0 = *(const half8*)kp;
    const half8 kf1 = *(const half8*)(kp + 32);
    floatx4 z = {0.f, 0.f, 0.f, 0.f};
    z = __builtin_amdgcn_mfma_f32_16x16x32_f16(kf0, qa, z, 0, 0, 0);
    const floatx4 sa = __builtin_amdgcn_mfma_f32_16x16x32_f16(kf1, qb, z, 0, 0, 0);
    const half4 ph = *(const half4*)&slot[l * Vs + st * 16 + quad * 4];  // 1 b64
    const bool dg = (st == diagSt);
    const float e0 = (!dg || 4 * quad + 0 <= l) ? __expf(sa[0] + (float)ph[0]) : 0.f;
    const float e1 = (!dg || 4 * quad + 1 <= l) ? __expf(sa[1] + (float)ph[1]) : 0.f;
    const float e2 = (!dg || 4 * quad + 2 <= l) ? __expf(sa[2] + (float)ph[2]) : 0.f;
    const float e3 = (!dg || 4 * quad + 3 <= l) ? __expf(sa[3] + (float)ph[3]) : 0.f;
    sum += e0 + e1 + e2 + e3;
    union { fp16x2 h; unsigned u; } ua, ub;
    ua.h = __builtin_amdgcn_cvt_pkrtz(e0, e1);
    ub.h = __builtin_amdgcn_cvt_pkrtz(e2, e3);
    pk0 = ua.u; pk1 = ub.u;
}

// shuffle 2 score tiles (C-layout) into the PV B-frag (P^T), swapped PV
__device__ __forceinline__ void pv_chunk(
    const _Float16* __restrict__ VT, int c, int l, int quad, int srcA, bool hi2,
    unsigned p10, unsigned p11, unsigned p20, unsigned p21, floatx4* oa)
{
    const unsigned a0 = (unsigned)__shfl((int)p10, srcA);
    const unsigned a1 = (unsigned)__shfl((int)p11, srcA);
    const unsigned a2 = (unsigned)__shfl((int)p10, srcA + 16);
    const unsigned a3 = (unsigned)__shfl((int)p11, srcA + 16);
    const unsigned b0 = (unsigned)__shfl((int)p20, srcA);
    const unsigned b1 = (unsigned)__shfl((int)p21, srcA);
    const unsigned b2 = (unsigned)__shfl((int)p20, srcA + 16);
    const unsigned b3 = (unsigned)__shfl((int)p21, srcA + 16);
    union { unsigned u[4]; half8 v; } pb;
    pb.u[0] = hi2 ? b0 : a0; pb.u[1] = hi2 ? b1 : a1;
    pb.u[2] = hi2 ? b2 : a2; pb.u[3] = hi2 ? b3 : a3;
#pragma unroll
    for (int ht = 0; ht < 4; ++ht) {
        const half8 vf = *(const half8*)&VT[(ht * 16 + l) * 264 + c * 32 + quad * 8];
        oa[ht] = __builtin_amdgcn_mfma_f32_16x16x32_f16(vf, pb.v, oa[ht], 0, 0, 0);
    }
}

// ---------------------------------------------------------------------------
// fused r25: in-register P.  r24 post-mortem: -3 barriers ~= neutral -> the
// stall is each wave's serial LDS chain (P made 3 LDS trips: scatter/exp
// scalar b16 x8 per tile + PV b128).  Here: content mfma SWAPPED (K,Q) so
// lane&15 = q, 4 s-values/lane; exp in-register (pos via ONE b64 read);
// cvt_pkrtz + 8 __shfl converts two score tiles directly into the PV B-frag
// (P^T); PV swapped mfma(V^T, P^T) -- same VT fragments as before.  P never
// touches LDS; causal mask + missing-subtile zeros are register predicates.
// Work split at st=8: own wave T does st<=7 (+diag tiles T<8), partner 15-T
// does st 8..T; pos band 8 split by store predicate (own l+row<=14, partner
// >=15) -> every exp read is self-written, B4/B5 eliminated.  Partner waves
// pass tile>=8 O-partials through the (dead) slot space: 2-barrier merge.
// Klds stride 72->76 (spreads the b128 K-read banks).  Phase 1 = r24.
// Barriers: S1,S2,S3,B3,Bm1,Bm2 = 6.
// ---------------------------------------------------------------------------
__global__ __launch_bounds__(1024, 4) void fused(
    const float* __restrict__ x, const _Float16* __restrict__ WT,
    const _Float16* __restrict__ rpeh, float* __restrict__ out)
{
    __shared__ _Float16 lds[76288];        // 149 KB: K[256][76] | VT | pool
    __shared__ float rowsumP[256];         // partner row-sums (tiles 8..15)
    _Float16* Klds = lds;                  // [256][76]
    _Float16* VT   = lds + 19456;          // [64][264]
    _Float16* pool = lds + 36352;          // 39936 halves (W c0 / pos slots)

    const int tid  = threadIdx.x;
    const int b    = blockIdx.x;
    const int w    = tid >> 6;
    const int lane = tid & 63;
    const int quad = lane >> 4;
    const int l    = lane & 15;

    union H8 { half8 v; fp16x2 p[4]; };
    const float4* xg = reinterpret_cast<const float4*>(x);
    const int row0g = b * 256 + w * 16;    // wave's 16 x-rows

    floatx4 acc[12];
#pragma unroll
    for (int nt = 0; nt < 12; ++nt) acc[nt] = (floatx4){0.f, 0.f, 0.f, 0.f};

    // ---- phase 1: stage BOTH W chunks, one long compute region (r24) -----
    {
#pragma unroll
        for (int i = 0; i < 3; ++i) {
            const int gi  = tid + i * 1024;
            const int row = gi >> 4;
            const int g   = gi & 15;
            const _Float16* src = WT + (size_t)row * 256 + g * 8;
            *(half8*)&pool[row * 136 + g * 8] = *(const half8*)src;
            *(half8*)&lds[row * 136 + g * 8]  = *(const half8*)(src + 128);
        }
        float4 xa[4][2];
#pragma unroll
        for (int kk = 0; kk < 4; ++kk) {
            const size_t base = (size_t)(row0g + l) * 64 + kk * 8 + quad * 2;
            xa[kk][0] = xg[base];
            xa[kk][1] = xg[base + 1];
        }
        __syncthreads();                   // S1: both W chunks staged

        float4 xb[4][2];
#pragma unroll
        for (int kk = 0; kk < 4; ++kk) {
            const size_t base = (size_t)(row0g + l) * 64 + 32 + kk * 8 + quad * 2;
            xb[kk][0] = xg[base];
            xb[kk][1] = xg[base + 1];
        }
#pragma unroll
        for (int kk = 0; kk < 4; ++kk) {
            H8 u;
            u.p[0] = __builtin_amdgcn_cvt_pkrtz(xa[kk][0].x, xa[kk][0].y);
            u.p[1] = __builtin_amdgcn_cvt_pkrtz(xa[kk][0].z, xa[kk][0].w);
            u.p[2] = __builtin_amdgcn_cvt_pkrtz(xa[kk][1].x, xa[kk][1].y);
            u.p[3] = __builtin_amdgcn_cvt_pkrtz(xa[kk][1].z, xa[kk][1].w);
#pragma unroll
            for (int nt = 0; nt < 12; ++nt) {
                const half8 bf = *(const half8*)&pool[(nt * 16 + l) * 136 + kk * 32 + quad * 8];
                acc[nt] = __builtin_amdgcn_mfma_f32_16x16x32_f16(u.v, bf, acc[nt], 0, 0, 0);
            }
        }
#pragma unroll
        for (int kk = 0; kk < 4; ++kk) {
            H8 u;
            u.p[0] = __builtin_amdgcn_cvt_pkrtz(xb[kk][0].x, xb[kk][0].y);
            u.p[1] = __builtin_amdgcn_cvt_pkrtz(xb[kk][0].z, xb[kk][0].w);
            u.p[2] = __builtin_amdgcn_cvt_pkrtz(xb[kk][1].x, xb[kk][1].y);
            u.p[3] = __builtin_amdgcn_cvt_pkrtz(xb[kk][1].z, xb[kk][1].w);
#pragma unroll
            for (int nt = 0; nt < 12; ++nt) {
                const half8 bf = *(const half8*)&lds[(nt * 16 + l) * 136 + kk * 32 + quad * 8];
                acc[nt] = __builtin_amdgcn_mfma_f32_16x16x32_f16(u.v, bf, acc[nt], 0, 0, 0);
            }
        }
        __syncthreads();                   // S2: W readers done everywhere
    }

    // ---- epilogue: K (scaled, stride 76), VT, q-slot; one barrier --------
    _Float16* wh = pool + slot_off(w);
    const int Vw = slot_width(w);
    {
        const int trw = w * 16;
#pragma unroll
        for (int nt = 0; nt < 4; ++nt) {
#pragma unroll
            for (int r = 0; r < 4; ++r) {
                Klds[(trw + quad * 4 + r) * 76 + nt * 16 + l] = (_Float16)(acc[nt][r] * 0.125f);
                wh[(quad * 4 + r) * Vw + nt * 16 + l] = (_Float16)acc[nt + 4][r];
            }
            half4 vv;
            vv[0] = (_Float16)acc[nt + 8][0];
            vv[1] = (_Float16)acc[nt + 8][1];
            vv[2] = (_Float16)acc[nt + 8][2];
            vv[3] = (_Float16)acc[nt + 8][3];
            *(half4*)&VT[(nt * 16 + l) * 264 + trw + quad * 4] = vv;
        }
    }
    __syncthreads();       // S3: K/VT/q visible block-wide

    // q fragments: own + partner (B-operand layout, same per-lane addressing)
    const half8 qf0 = *(const half8*)&wh[l * Vw + quad * 8];
    const half8 qf1 = *(const half8*)&wh[l * Vw + 32 + quad * 8];
    const int tp = 15 - w;
    _Float16* whp = pool + slot_off(tp);
    const int Vp = slot_width(tp);
    half8 qg0 = qf0, qg1 = qf1;
    if (w < 8) {
        qg0 = *(const half8*)&whp[l * Vp + quad * 8];
        qg1 = *(const half8*)&whp[l * Vp + 32 + quad * 8];
    }
    __syncthreads();       // B3: q consumed; slots writable (pos scatter)

    // ---- pos scores, skewed scatter; band 8 split own/partner ------------
    const int jmaxo = (w < 8) ? w : 8;
#pragma unroll
    for (int j = 0; j < 9; ++j) {
        if (j <= jmaxo) {
            const int dt = j + 15 - w;
            const _Float16* rp = rpeh + (size_t)(dt * 16 + l) * HH + quad * 8;
            const half8 bf0 = *(const half8*)rp;
            const half8 bf1 = *(const half8*)(rp + 32);
            floatx4 z = {0.f, 0.f, 0.f, 0.f};
            z = __builtin_amdgcn_mfma_f32_16x16x32_f16(qf0, bf0, z, 0, 0, 0);
            const floatx4 pacc = __builtin_amdgcn_mfma_f32_16x16x32_f16(qf1, bf1, z, 0, 0, 0);
#pragma unroll
            for (int r = 0; r < 4; ++r) {
                const int row = quad * 4 + r;
                const int s   = 16 * j + l + row - 15;
                if (j == 0)      { if (s >= 0) wh[row * Vw + s] = (_Float16)pacc[r]; }
                else if (j == 8) { if (l + row <= 14) wh[row * Vw + s] = (_Float16)pacc[r]; }
                else               wh[row * Vw + s] = (_Float16)pacc[r];
            }
        }
    }
    if (w < 8) {           // partner: tile tp, band 8 (s>=128 part) + 9..tp
#pragma unroll
        for (int j = 8; j < 16; ++j) {
            if (j <= tp) {
                const int dt = j + w;
                const _Float16* rp = rpeh + (size_t)(dt * 16 + l) * HH + quad * 8;
                const half8 bf0 = *(const half8*)rp;
                const half8 bf1 = *(const half8*)(rp + 32);
                floatx4 z = {0.f, 0.f, 0.f, 0.f};
                z = __builtin_amdgcn_mfma_f32_16x16x32_f16(qg0, bf0, z, 0, 0, 0);
                const floatx4 pacc = __builtin_amdgcn_mfma_f32_16x16x32_f16(qg1, bf1, z, 0, 0, 0);
#pragma unroll
                for (int r = 0; r < 4; ++r) {
                    const int row = quad * 4 + r;
                    const int s   = 16 * j + l + row - 15;
                    if (j == 8) { if (l + row >= 15) whp[row * Vp + s] = (_Float16)pacc[r]; }
                    else          whp[row * Vp + s] = (_Float16)pacc[r];
                }
            }
        }
    }
    // no barrier: every pos value exp'd below was written by this wave

    // ---- content + exp + PV, all in-register -----------------------------
    const int srcA = l + ((quad & 1) << 5);
    const bool hi2 = (quad >= 2);
    float sumO = 0.f;
    floatx4 oacc[4] = {{0.f,0.f,0.f,0.f},{0.f,0.f,0.f,0.f},
                       {0.f,0.f,0.f,0.f},{0.f,0.f,0.f,0.f}};
    const int stmaxO = (w < 8) ? w : 7;
#pragma unroll
    for (int c = 0; c < 4; ++c) {
        if (c <= (stmaxO >> 1)) {
            unsigned p10, p11, p20 = 0u, p21 = 0u;
            score_exp(Klds, wh, Vw, 2 * c, w, l, quad, qf0, qf1, sumO, p10, p11);
            if (2 * c + 1 <= stmaxO)
                score_exp(Klds, wh, Vw, 2 * c + 1, w, l, quad, qf0, qf1, sumO, p20, p21);
            pv_chunk(VT, c, l, quad, srcA, hi2, p10, p11, p20, p21, oacc);
        }
    }
    float sumP = 0.f;
    floatx4 oaccP[4] = {{0.f,0.f,0.f,0.f},{0.f,0.f,0.f,0.f},
                        {0.f,0.f,0.f,0.f},{0.f,0.f,0.f,0.f}};
    if (w < 8) {           // partner: tile tp, st 8..tp
#pragma unroll
        for (int c = 4; c < 8; ++c) {
            if (c <= (tp >> 1)) {
                unsigned p10, p11, p20 = 0u, p21 = 0u;
                score_exp(Klds, whp, Vp, 2 * c, tp, l, quad, qg0, qg1, sumP, p10, p11);
                if (2 * c + 1 <= tp)
                    score_exp(Klds, whp, Vp, 2 * c + 1, tp, l, quad, qg0, qg1, sumP, p20, p21);
                pv_chunk(VT, c, l, quad, srcA, hi2, p10, p11, p20, p21, oaccP);
            }
        }
        sumP += __shfl_xor(sumP, 16);
        sumP += __shfl_xor(sumP, 32);
    }
    sumO += __shfl_xor(sumO, 16);
    sumO += __shfl_xor(sumO, 32);

    __syncthreads();       // Bm1: all exp-slot reads + PV done
    if (w < 8) {           // pass tile-tp partials through dead slot space
        float* ob = (float*)(pool + slot_off(tp));
#pragma unroll
        for (int ht = 0; ht < 4; ++ht)
            *(floatx4*)&ob[l * 68 + ht * 16 + quad * 4] = oaccP[ht];
        if (lane < 16) rowsumP[16 * tp + lane] = sumP;
    }
    __syncthreads();       // Bm2: partials visible

    float inv;
    if (w >= 8) {
        const float* ob = (const float*)(pool + slot_off(w));
#pragma unroll
        for (int ht = 0; ht < 4; ++ht)
            oacc[ht] += *(const floatx4*)&ob[l * 68 + ht * 16 + quad * 4];
        inv = 1.0f / (sumO + rowsumP[16 * w + l]);
    } else {
        inv = 1.0f / sumO;
    }
#pragma unroll
    for (int ht = 0; ht < 4; ++ht) {
        float4 o;
        o.x = oacc[ht][0] * inv;
        o.y = oacc[ht][1] * inv;
        o.z = oacc[ht][2] * inv;
        o.w = oacc[ht][3] * inv;
        *(float4*)&out[(size_t)(b * 256 + 16 * w + l) * 64 + ht * 16 + quad * 4] = o;
    }
}

extern "C" void kernel_launch(void* const* d_in, const int* in_sizes, int n_in,
                              void* d_out, int out_size, void* d_ws, size_t ws_size,
                              hipStream_t stream) {
    const float* x   = (const float*)d_in[0];
    const float* Wk  = (const float*)d_in[1];
    const float* Wq  = (const float*)d_in[2];
    const float* Wv  = (const float*)d_in[3];
    const float* rpe = (const float*)d_in[4];
    float* out = (float*)d_out;

    _Float16* rpeh = (_Float16*)d_ws;              // [256][64]
    _Float16* WT   = rpeh + 256 * HH;              // [192][256]

    prep<<<dim3(256), dim3(256), 0, stream>>>(rpe, Wk, Wq, Wv, rpeh, WT);
    fused<<<dim3(BB), dim3(1024), 0, stream>>>(x, WT, rpeh, out);
}